// Round 1
// baseline (1686.519 us; speedup 1.0000x reference)
//
#include <hip/hip_runtime.h>
#include <cstdint>
#include <cstddef>

#define N_TOTAL 21760
#define BATCH   2
#define M_TOT   (BATCH * N_TOTAL)   // 43520
#define DMODEL  256
#define NHEAD   8
#define HDIM    32
#define FFN     1024

// ---------------------------------------------------------------- LayerNorm
__global__ void ln_kernel(const float* __restrict__ x, const float* __restrict__ w,
                          const float* __restrict__ b, float* __restrict__ y) {
  int tkn = blockIdx.x;
  int t   = threadIdx.x;
  size_t base = (size_t)tkn * DMODEL;
  float v  = x[base + t];
  float s1 = v, s2 = v * v;
  #pragma unroll
  for (int off = 32; off; off >>= 1) {
    s1 += __shfl_down(s1, off);
    s2 += __shfl_down(s2, off);
  }
  __shared__ float r1[4], r2[4];
  int wid = t >> 6, lane = t & 63;
  if (lane == 0) { r1[wid] = s1; r2[wid] = s2; }
  __syncthreads();
  float tot1 = r1[0] + r1[1] + r1[2] + r1[3];
  float tot2 = r2[0] + r2[1] + r2[2] + r2[3];
  float m   = tot1 * (1.0f / DMODEL);
  float var = tot2 * (1.0f / DMODEL) - m * m;
  float rs  = rsqrtf(var + 1e-5f);
  y[base + t] = (v - m) * rs * w[t] + b[t];
}

// ------------------------------------------------- generic fp32 tiled GEMM
// C[M x ncols] = act(A[M x K] @ W[K x ncols] + bias) (+ addsrc)
// BM=64, BN=64, BK=128, 256 threads, 4x4 per thread.
__global__ void gemm_kernel(const float* __restrict__ A, const float* __restrict__ W,
                            const float* __restrict__ bias, const float* __restrict__ addsrc,
                            float* __restrict__ C, int K, int ncols, int relu) {
  __shared__ float As[128 * 64];   // [k][row]
  __shared__ float Ws[128 * 64];   // [k][col]
  int t    = threadIdx.x;
  int row0 = blockIdx.x * 64;
  int col0 = blockIdx.y * 64;
  int ar = t >> 2, aq = t & 3;          // A staging
  int wc = (t & 15) << 2, wr = t >> 4;  // W staging
  int ty = t >> 4, tx = t & 15;
  float acc[4][4] = {};
  for (int k0 = 0; k0 < K; k0 += 128) {
    const float* Ap = A + (size_t)(row0 + ar) * K + k0 + aq * 32;
    #pragma unroll
    for (int i = 0; i < 8; ++i) {
      float4 v = *(const float4*)(Ap + i * 4);
      int k = aq * 32 + i * 4;
      As[(k + 0) * 64 + ar] = v.x;
      As[(k + 1) * 64 + ar] = v.y;
      As[(k + 2) * 64 + ar] = v.z;
      As[(k + 3) * 64 + ar] = v.w;
    }
    #pragma unroll
    for (int p = 0; p < 8; ++p) {
      int k = p * 16 + wr;
      *(float4*)&Ws[k * 64 + wc] =
          *(const float4*)(W + (size_t)(k0 + k) * ncols + col0 + wc);
    }
    __syncthreads();
    #pragma unroll 8
    for (int k = 0; k < 128; ++k) {
      float4 a = *(const float4*)&As[k * 64 + ty * 4];
      float4 b = *(const float4*)&Ws[k * 64 + tx * 4];
      float av[4] = {a.x, a.y, a.z, a.w};
      float bv[4] = {b.x, b.y, b.z, b.w};
      #pragma unroll
      for (int i = 0; i < 4; ++i)
        #pragma unroll
        for (int j = 0; j < 4; ++j) acc[i][j] += av[i] * bv[j];
    }
    __syncthreads();
  }
  float4 bb = *(const float4*)&bias[col0 + tx * 4];
  float bvv[4] = {bb.x, bb.y, bb.z, bb.w};
  #pragma unroll
  for (int i = 0; i < 4; ++i) {
    int r = row0 + ty * 4 + i;
    float o[4];
    #pragma unroll
    for (int j = 0; j < 4; ++j) {
      o[j] = acc[i][j] + bvv[j];
      if (relu) o[j] = fmaxf(o[j], 0.0f);
    }
    if (addsrc) {
      float4 s = *(const float4*)&addsrc[(size_t)r * ncols + col0 + tx * 4];
      o[0] += s.x; o[1] += s.y; o[2] += s.z; o[3] += s.w;
    }
    float4 ov = {o[0], o[1], o[2], o[3]};
    *(float4*)&C[(size_t)r * ncols + col0 + tx * 4] = ov;
  }
}

// ------------------------------------------- fused projection GEMM (v / q)
// col-tiles 0..3: value = v @ Wv ; 4..7: off = q @ Woff ; 8..9: aw = q @ Wattn
__global__ void gemm_proj(const float* __restrict__ v, const float* __restrict__ pos,
                          const float* __restrict__ Wv, const float* __restrict__ bv,
                          const float* __restrict__ Woff, const float* __restrict__ boff,
                          const float* __restrict__ Wattn, const float* __restrict__ battn,
                          float* __restrict__ value, float* __restrict__ offraw,
                          float* __restrict__ awraw) {
  __shared__ float As[128 * 64];
  __shared__ float Ws[128 * 64];
  int t    = threadIdx.x;
  int row0 = blockIdx.x * 64;
  int cb   = blockIdx.y;   // 0..9
  const float* W; const float* bias; float* C; int wcol0; int nc; bool useq;
  if (cb < 4)      { W = Wv;    bias = bv;    C = value;  wcol0 = cb * 64;       nc = 256; useq = false; }
  else if (cb < 8) { W = Woff;  bias = boff;  C = offraw; wcol0 = (cb - 4) * 64; nc = 256; useq = true;  }
  else             { W = Wattn; bias = battn; C = awraw;  wcol0 = (cb - 8) * 64; nc = 128; useq = true;  }
  int ar = t >> 2, aq = t & 3;
  int wc = (t & 15) << 2, wr = t >> 4;
  int ty = t >> 4, tx = t & 15;
  float acc[4][4] = {};
  for (int k0 = 0; k0 < 256; k0 += 128) {
    const float* Ap = v + (size_t)(row0 + ar) * 256 + k0 + aq * 32;
    const float* Pp = pos + (size_t)(row0 + ar) * 256 + k0 + aq * 32;
    #pragma unroll
    for (int i = 0; i < 8; ++i) {
      float4 a = *(const float4*)(Ap + i * 4);
      if (useq) {
        float4 p = *(const float4*)(Pp + i * 4);
        a.x += p.x; a.y += p.y; a.z += p.z; a.w += p.w;
      }
      int k = aq * 32 + i * 4;
      As[(k + 0) * 64 + ar] = a.x;
      As[(k + 1) * 64 + ar] = a.y;
      As[(k + 2) * 64 + ar] = a.z;
      As[(k + 3) * 64 + ar] = a.w;
    }
    #pragma unroll
    for (int p = 0; p < 8; ++p) {
      int k = p * 16 + wr;
      *(float4*)&Ws[k * 64 + wc] =
          *(const float4*)(W + (size_t)(k0 + k) * nc + wcol0 + wc);
    }
    __syncthreads();
    #pragma unroll 8
    for (int k = 0; k < 128; ++k) {
      float4 a = *(const float4*)&As[k * 64 + ty * 4];
      float4 b = *(const float4*)&Ws[k * 64 + tx * 4];
      float av[4] = {a.x, a.y, a.z, a.w};
      float bvv[4] = {b.x, b.y, b.z, b.w};
      #pragma unroll
      for (int i = 0; i < 4; ++i)
        #pragma unroll
        for (int j = 0; j < 4; ++j) acc[i][j] += av[i] * bvv[j];
    }
    __syncthreads();
  }
  float4 bb = *(const float4*)&bias[wcol0 + tx * 4];
  float bvv[4] = {bb.x, bb.y, bb.z, bb.w};
  #pragma unroll
  for (int i = 0; i < 4; ++i) {
    int r = row0 + ty * 4 + i;
    float4 ov = {acc[i][0] + bvv[0], acc[i][1] + bvv[1],
                 acc[i][2] + bvv[2], acc[i][3] + bvv[3]};
    *(float4*)&C[(size_t)r * nc + wcol0 + tx * 4] = ov;
  }
}

// --------------------------------------------------- MSDA sampling + softmax
// one block per token; thread = (h, d); softmax over 16 logits inline.
__global__ void msda_kernel(const float* __restrict__ value, const float* __restrict__ offraw,
                            const float* __restrict__ awraw, const float* __restrict__ ref,
                            float* __restrict__ out) {
  int tkn = blockIdx.x;
  int t   = threadIdx.x;
  int h = t >> 5, d = t & 31;
  int b = tkn / N_TOTAL;
  size_t vbase_b = (size_t)b * N_TOTAL;

  const float* lg = awraw + (size_t)tkn * 128 + h * 16;
  float mx = lg[0];
  #pragma unroll
  for (int i = 1; i < 16; ++i) mx = fmaxf(mx, lg[i]);
  float e[16]; float s = 0.f;
  #pragma unroll
  for (int i = 0; i < 16; ++i) { e[i] = __expf(lg[i] - mx); s += e[i]; }
  float inv = 1.0f / s;

  const float* offp = offraw + (size_t)tkn * 256 + h * 32;
  const float* rp   = ref + (size_t)tkn * 8;
  const int startl[4] = {0, 16384, 20480, 21504};
  const int HL[4]     = {128, 64, 32, 16};
  const int dyA[4] = {0, 0, 1, 1}, dxA[4] = {0, 1, 0, 1};

  float acc = 0.f;
  #pragma unroll
  for (int l = 0; l < 4; ++l) {
    int Wl = HL[l], Hl = HL[l];
    float rx = rp[l * 2 + 0], ry = rp[l * 2 + 1];
    int base = startl[l];
    #pragma unroll
    for (int p = 0; p < 4; ++p) {
      float ox = offp[l * 8 + p * 2 + 0], oy = offp[l * 8 + p * 2 + 1];
      float aw = e[l * 4 + p] * inv;
      float x = rx * (float)Wl + ox - 0.5f;
      float y = ry * (float)Hl + oy - 0.5f;
      float x0f = floorf(x), y0f = floorf(y);
      float wx = x - x0f, wy = y - y0f;
      int x0 = (int)x0f, y0 = (int)y0f;
      float wt[4] = {(1.f - wx) * (1.f - wy), wx * (1.f - wy),
                     (1.f - wx) * wy, wx * wy};
      #pragma unroll
      for (int tp = 0; tp < 4; ++tp) {
        int xi = x0 + dxA[tp], yi = y0 + dyA[tp];
        if (xi >= 0 && xi < Wl && yi >= 0 && yi < Hl) {
          size_t vidx = ((vbase_b + base + (size_t)(yi * Wl + xi)) * NHEAD + h) * HDIM + d;
          acc += aw * wt[tp] * value[vidx];
        }
      }
    }
  }
  out[(size_t)tkn * DMODEL + h * HDIM + d] = acc;
}

// --------------------------------------------------------------- launcher
extern "C" void kernel_launch(void* const* d_in, const int* in_sizes, int n_in,
                              void* d_out, int out_size, void* d_ws, size_t ws_size,
                              hipStream_t stream) {
  const float* embed = (const float*)d_in[0];
  const float* pos   = (const float*)d_in[1];
  const float* refp  = (const float*)d_in[2];
  const float* ln1w  = (const float*)d_in[3];
  const float* ln1b  = (const float*)d_in[4];
  const float* ln2w  = (const float*)d_in[5];
  const float* ln2b  = (const float*)d_in[6];
  const float* Wv    = (const float*)d_in[7];
  const float* bv    = (const float*)d_in[8];
  const float* Woff  = (const float*)d_in[9];
  const float* boff  = (const float*)d_in[10];
  const float* Wattn = (const float*)d_in[11];
  const float* battn = (const float*)d_in[12];
  const float* Wo    = (const float*)d_in[13];
  const float* bo    = (const float*)d_in[14];
  const float* W1    = (const float*)d_in[15];
  const float* b1    = (const float*)d_in[16];
  const float* W2    = (const float*)d_in[17];
  const float* b2    = (const float*)d_in[18];
  float* out = (float*)d_out;
  float* ws  = (float*)d_ws;

  const size_t U = (size_t)M_TOT * DMODEL;  // 11,141,120 floats
  float* vbuf   = ws;               // [0, 1U)   v, later f
  float* valbuf = ws + U;           // [1U, 2U)
  float* offbuf = ws + 2 * U;       // [2U, 3U)
  float* awbuf  = ws + 3 * U;       // [3U, 3.5U)
  float* msda   = ws + 3 * U + U / 2; // [3.5U, 4.5U)
  float* embed2 = ws + 5 * U;       // [5U, 6U)
  float* fbuf   = ws;               // reuse of vbuf
  float* hidden = ws + U;           // [1U, 5U) reuse (valbuf..msda dead)

  ln_kernel<<<M_TOT, 256, 0, stream>>>(embed, ln1w, ln1b, vbuf);
  gemm_proj<<<dim3(M_TOT / 64, 10), 256, 0, stream>>>(
      vbuf, pos, Wv, bv, Woff, boff, Wattn, battn, valbuf, offbuf, awbuf);
  msda_kernel<<<M_TOT, 256, 0, stream>>>(valbuf, offbuf, awbuf, refp, msda);
  gemm_kernel<<<dim3(M_TOT / 64, 4), 256, 0, stream>>>(
      msda, Wo, bo, embed, embed2, 256, 256, 0);
  ln_kernel<<<M_TOT, 256, 0, stream>>>(embed2, ln2w, ln2b, fbuf);
  gemm_kernel<<<dim3(M_TOT / 64, 16), 256, 0, stream>>>(
      fbuf, W1, b1, nullptr, hidden, 256, 1024, 1);
  gemm_kernel<<<dim3(M_TOT / 64, 4), 256, 0, stream>>>(
      hidden, W2, b2, embed2, out, 1024, 256, 0);
}

// Round 2
// 454.829 us; speedup vs baseline: 3.7080x; 3.7080x over previous
//
#include <hip/hip_runtime.h>
#include <cstdint>
#include <cstddef>

#define N_TOTAL 21760
#define BATCH   2
#define M_TOT   (BATCH * N_TOTAL)   // 43520
#define DMODEL  256
#define NHEAD   8
#define HDIM    32
#define FFN     1024

typedef __bf16 b16x8 __attribute__((ext_vector_type(8)));
typedef float  f32x4 __attribute__((ext_vector_type(4)));

// fp32 -> bf16 RNE
__device__ __forceinline__ unsigned short f2b(float f) {
  union { float f; unsigned u; } v; v.f = f;
  unsigned r = v.u + 0x7FFF + ((v.u >> 16) & 1);
  return (unsigned short)(r >> 16);
}

// ---------------------------------------------- weight convert + transpose
// src fp32 [K][N] row-major -> dst bf16 [N][K] row-major
__global__ void wconv_kernel(const float* __restrict__ src, unsigned short* __restrict__ dst,
                             int K, int N) {
  int idx = blockIdx.x * 256 + threadIdx.x;
  if (idx >= K * N) return;
  int k = idx / N, n = idx - k * N;
  dst[(size_t)n * K + k] = f2b(src[idx]);
}

// ---------------------------------------------------------------- LayerNorm
// LN1: writes v (bf16) and q = v + pos (bf16)
__global__ void ln1_kernel(const float* __restrict__ x, const float* __restrict__ pos,
                           const float* __restrict__ w, const float* __restrict__ b,
                           unsigned short* __restrict__ vb, unsigned short* __restrict__ qb) {
  int tkn = blockIdx.x;
  int t   = threadIdx.x;
  size_t base = (size_t)tkn * DMODEL;
  float v  = x[base + t];
  float s1 = v, s2 = v * v;
  #pragma unroll
  for (int off = 32; off; off >>= 1) {
    s1 += __shfl_down(s1, off);
    s2 += __shfl_down(s2, off);
  }
  __shared__ float r1[4], r2[4];
  int wid = t >> 6, lane = t & 63;
  if (lane == 0) { r1[wid] = s1; r2[wid] = s2; }
  __syncthreads();
  float tot1 = r1[0] + r1[1] + r1[2] + r1[3];
  float tot2 = r2[0] + r2[1] + r2[2] + r2[3];
  float m   = tot1 * (1.0f / DMODEL);
  float var = tot2 * (1.0f / DMODEL) - m * m;
  float rs  = rsqrtf(var + 1e-5f);
  float o = (v - m) * rs * w[t] + b[t];
  vb[base + t] = f2b(o);
  qb[base + t] = f2b(o + pos[base + t]);
}

// LN2: bf16 out only
__global__ void ln2_kernel(const float* __restrict__ x, const float* __restrict__ w,
                           const float* __restrict__ b, unsigned short* __restrict__ yb) {
  int tkn = blockIdx.x;
  int t   = threadIdx.x;
  size_t base = (size_t)tkn * DMODEL;
  float v  = x[base + t];
  float s1 = v, s2 = v * v;
  #pragma unroll
  for (int off = 32; off; off >>= 1) {
    s1 += __shfl_down(s1, off);
    s2 += __shfl_down(s2, off);
  }
  __shared__ float r1[4], r2[4];
  int wid = t >> 6, lane = t & 63;
  if (lane == 0) { r1[wid] = s1; r2[wid] = s2; }
  __syncthreads();
  float tot1 = r1[0] + r1[1] + r1[2] + r1[3];
  float tot2 = r2[0] + r2[1] + r2[2] + r2[3];
  float m   = tot1 * (1.0f / DMODEL);
  float var = tot2 * (1.0f / DMODEL) - m * m;
  float rs  = rsqrtf(var + 1e-5f);
  yb[base + t] = f2b((v - m) * rs * w[t] + b[t]);
}

// ------------------------------------------------------- bf16 MFMA GEMM
// C[M x N] = act(A[M x K] @ Bt[N x K]^T + bias) (+ addsrc)
// tile 128x128, BK=64, 256 threads (4 waves, each 64x64 = 4x4 frags 16x16x32)
__global__ void gemm_bf16(const unsigned short* __restrict__ A,
                          const unsigned short* __restrict__ Bt,
                          const float* __restrict__ bias, const float* __restrict__ addsrc,
                          float* __restrict__ Cf, unsigned short* __restrict__ Cb,
                          int K, int N, int relu) {
  __shared__ unsigned short As[128 * 72];
  __shared__ unsigned short Bs[128 * 72];
  int t    = threadIdx.x;
  int row0 = blockIdx.x * 128;
  int col0 = blockIdx.y * 128;
  int w    = t >> 6;
  int l    = t & 63;
  int wm   = w >> 1, wn = w & 1;
  int lr   = l & 15;       // frag row/col within 16
  int kq   = l >> 4;       // 0..3

  f32x4 acc[4][4];
  #pragma unroll
  for (int i = 0; i < 4; ++i)
    #pragma unroll
    for (int j = 0; j < 4; ++j) acc[i][j] = (f32x4){0.f, 0.f, 0.f, 0.f};

  for (int k0 = 0; k0 < K; k0 += 64) {
    #pragma unroll
    for (int i = 0; i < 4; ++i) {
      int c = i * 256 + t;           // 1024 chunks of 8 bf16
      int row = c >> 3, seg = c & 7;
      float4 va = *(const float4*)&A [(size_t)(row0 + row) * K + k0 + seg * 8];
      float4 vb = *(const float4*)&Bt[(size_t)(col0 + row) * K + k0 + seg * 8];
      *(float4*)&As[row * 72 + seg * 8] = va;
      *(float4*)&Bs[row * 72 + seg * 8] = vb;
    }
    __syncthreads();
    #pragma unroll
    for (int kk = 0; kk < 2; ++kk) {
      b16x8 aF[4], bF[4];
      #pragma unroll
      for (int i = 0; i < 4; ++i)
        aF[i] = *(const b16x8*)&As[(wm * 64 + i * 16 + lr) * 72 + kk * 32 + kq * 8];
      #pragma unroll
      for (int j = 0; j < 4; ++j)
        bF[j] = *(const b16x8*)&Bs[(wn * 64 + j * 16 + lr) * 72 + kk * 32 + kq * 8];
      #pragma unroll
      for (int i = 0; i < 4; ++i)
        #pragma unroll
        for (int j = 0; j < 4; ++j)
          acc[i][j] = __builtin_amdgcn_mfma_f32_16x16x32_bf16(aF[i], bF[j], acc[i][j], 0, 0, 0);
    }
    __syncthreads();
  }

  // epilogue: C[row=(l>>4)*4+r][col=l&15] per frag
  #pragma unroll
  for (int j = 0; j < 4; ++j) {
    int colg = col0 + wn * 64 + j * 16 + lr;
    float bcol = bias[colg];
    #pragma unroll
    for (int i = 0; i < 4; ++i) {
      int r0g = row0 + wm * 64 + i * 16 + kq * 4;
      #pragma unroll
      for (int r = 0; r < 4; ++r) {
        int rowg = r0g + r;
        float o = acc[i][j][r] + bcol;
        if (relu) o = fmaxf(o, 0.0f);
        if (addsrc) o += addsrc[(size_t)rowg * N + colg];
        if (Cf) Cf[(size_t)rowg * N + colg] = o;
        if (Cb) Cb[(size_t)rowg * N + colg] = f2b(o);
      }
    }
  }
}

// --------------------------------------------------- MSDA sampling + softmax
// block = token. Phase 1 (128 thr): per (head,sample) weight+index -> LDS.
// Phase 2 (256 thr = head x d): pure gather + fma.
__global__ void msda_kernel(const float* __restrict__ value, const float* __restrict__ offraw,
                            const float* __restrict__ awraw, const float* __restrict__ ref,
                            unsigned short* __restrict__ outb) {
  __shared__ float wS[512];
  __shared__ int   iS[512];
  int tkn = blockIdx.x;
  int t   = threadIdx.x;
  int b   = (tkn >= N_TOTAL) ? 1 : 0;

  if (t < 128) {
    int h = t >> 4, s = t & 15, lev = s >> 2, p = s & 3;
    float lg = awraw[(size_t)tkn * 128 + h * 16 + s];
    float mx = lg;
    #pragma unroll
    for (int m = 1; m < 16; m <<= 1) mx = fmaxf(mx, __shfl_xor(mx, m, 16));
    float e = __expf(lg - mx);
    float sum = e;
    #pragma unroll
    for (int m = 1; m < 16; m <<= 1) sum += __shfl_xor(sum, m, 16);
    float aw = e / sum;

    const int HL[4] = {128, 64, 32, 16};
    const int ST[4] = {0, 16384, 20480, 21504};
    int Wl = HL[lev];
    float rx = ref[(size_t)tkn * 8 + lev * 2 + 0];
    float ry = ref[(size_t)tkn * 8 + lev * 2 + 1];
    float ox = offraw[(size_t)tkn * 256 + h * 32 + lev * 8 + p * 2 + 0];
    float oy = offraw[(size_t)tkn * 256 + h * 32 + lev * 8 + p * 2 + 1];
    float x = rx * (float)Wl + ox - 0.5f;   // Hl == Wl for all levels
    float y = ry * (float)Wl + oy - 0.5f;
    float x0f = floorf(x), y0f = floorf(y);
    float wx = x - x0f, wy = y - y0f;
    int x0 = (int)x0f, y0 = (int)y0f;
    float wt[4] = {(1.f - wx) * (1.f - wy), wx * (1.f - wy),
                   (1.f - wx) * wy, wx * wy};
    int base = b * N_TOTAL + ST[lev];
    #pragma unroll
    for (int tp = 0; tp < 4; ++tp) {
      int xi = x0 + (tp & 1), yi = y0 + (tp >> 1);
      bool ok = (xi >= 0) & (xi < Wl) & (yi >= 0) & (yi < Wl);
      wS[t * 4 + tp] = ok ? aw * wt[tp] : 0.f;
      iS[t * 4 + tp] = ok ? ((base + yi * Wl + xi) * 256 + h * 32) : 0;
    }
  }
  __syncthreads();

  int h = t >> 5, d = t & 31;
  int o = h * 64;
  float acc = 0.f;
  #pragma unroll 8
  for (int j = 0; j < 64; ++j) {
    acc += wS[o + j] * value[(size_t)iS[o + j] + d];
  }
  outb[(size_t)tkn * 256 + h * 32 + d] = f2b(acc);
}

// --------------------------------------------------------------- launcher
extern "C" void kernel_launch(void* const* d_in, const int* in_sizes, int n_in,
                              void* d_out, int out_size, void* d_ws, size_t ws_size,
                              hipStream_t stream) {
  const float* embed = (const float*)d_in[0];
  const float* pos   = (const float*)d_in[1];
  const float* refp  = (const float*)d_in[2];
  const float* ln1w  = (const float*)d_in[3];
  const float* ln1b  = (const float*)d_in[4];
  const float* ln2w  = (const float*)d_in[5];
  const float* ln2b  = (const float*)d_in[6];
  const float* Wv    = (const float*)d_in[7];
  const float* bv    = (const float*)d_in[8];
  const float* Woff  = (const float*)d_in[9];
  const float* boff  = (const float*)d_in[10];
  const float* Wattn = (const float*)d_in[11];
  const float* battn = (const float*)d_in[12];
  const float* Wo    = (const float*)d_in[13];
  const float* bo    = (const float*)d_in[14];
  const float* W1    = (const float*)d_in[15];
  const float* b1    = (const float*)d_in[16];
  const float* W2    = (const float*)d_in[17];
  const float* b2    = (const float*)d_in[18];
  float* out = (float*)d_out;
  float* ws  = (float*)d_ws;

  const size_t U = (size_t)M_TOT * DMODEL;  // 11,141,120 floats
  float* value  = ws;                 // [0, 1U)  fp32
  float* offraw = ws + U;             // [1U, 2U) fp32
  float* awraw  = ws + 2 * U;         // [2U, 2.5U) fp32
  float* embed2 = ws + 2 * U + U / 2; // [2.5U, 3.5U) fp32
  unsigned short* vb16  = (unsigned short*)(ws + 3 * U + U / 2);  // 0.5U floats
  unsigned short* qb16  = (unsigned short*)(ws + 4 * U);
  unsigned short* msdab = (unsigned short*)(ws + 4 * U + U / 2);
  unsigned short* fb16  = (unsigned short*)(ws + 5 * U);
  unsigned short* wbuf  = (unsigned short*)(ws + 5 * U + U / 2);
  // hidden bf16 overlays value+offraw (dead after msda): 43520*1024 ushorts = 2U floats
  unsigned short* hid16 = (unsigned short*)ws;

  unsigned short* Wvt    = wbuf;                 // 256*256
  unsigned short* Wofft  = Wvt + 65536;          // 256*256
  unsigned short* Wattnt = Wofft + 65536;        // 128*256
  unsigned short* Wot    = Wattnt + 32768;       // 256*256
  unsigned short* W1t    = Wot + 65536;          // 1024*256
  unsigned short* W2t    = W1t + 262144;         // 256*1024

  wconv_kernel<<<(65536 + 255) / 256, 256, 0, stream>>>(Wv, Wvt, 256, 256);
  wconv_kernel<<<(65536 + 255) / 256, 256, 0, stream>>>(Woff, Wofft, 256, 256);
  wconv_kernel<<<(32768 + 255) / 256, 256, 0, stream>>>(Wattn, Wattnt, 256, 128);
  wconv_kernel<<<(65536 + 255) / 256, 256, 0, stream>>>(Wo, Wot, 256, 256);
  wconv_kernel<<<(262144 + 255) / 256, 256, 0, stream>>>(W1, W1t, 256, 1024);
  wconv_kernel<<<(262144 + 255) / 256, 256, 0, stream>>>(W2, W2t, 1024, 256);

  ln1_kernel<<<M_TOT, 256, 0, stream>>>(embed, pos, ln1w, ln1b, vb16, qb16);

  gemm_bf16<<<dim3(M_TOT / 128, 2), 256, 0, stream>>>(
      vb16, Wvt, bv, nullptr, value, nullptr, 256, 256, 0);
  gemm_bf16<<<dim3(M_TOT / 128, 2), 256, 0, stream>>>(
      qb16, Wofft, boff, nullptr, offraw, nullptr, 256, 256, 0);
  gemm_bf16<<<dim3(M_TOT / 128, 1), 256, 0, stream>>>(
      qb16, Wattnt, battn, nullptr, awraw, nullptr, 256, 128, 0);

  msda_kernel<<<M_TOT, 256, 0, stream>>>(value, offraw, awraw, refp, msdab);

  gemm_bf16<<<dim3(M_TOT / 128, 2), 256, 0, stream>>>(
      msdab, Wot, bo, embed, embed2, nullptr, 256, 256, 0);

  ln2_kernel<<<M_TOT, 256, 0, stream>>>(embed2, ln2w, ln2b, fb16);

  gemm_bf16<<<dim3(M_TOT / 128, 8), 256, 0, stream>>>(
      fb16, W1t, b1, nullptr, nullptr, hid16, 256, 1024, 1);
  gemm_bf16<<<dim3(M_TOT / 128, 2), 256, 0, stream>>>(
      hid16, W2t, b2, embed2, out, nullptr, 1024, 256, 0);
}

// Round 4
// 354.180 us; speedup vs baseline: 4.7618x; 1.2842x over previous
//
#include <hip/hip_runtime.h>
#include <cstdint>
#include <cstddef>

#define N_TOTAL 21760
#define BATCH   2
#define M_TOT   (BATCH * N_TOTAL)   // 43520
#define DMODEL  256
#define NHEAD   8
#define HDIM    32
#define FFN     1024

typedef __bf16 b16x8 __attribute__((ext_vector_type(8)));
typedef float  f32x4 __attribute__((ext_vector_type(4)));

// fp32 -> bf16 RNE
__device__ __forceinline__ unsigned short f2b(float f) {
  union { float f; unsigned u; } v; v.f = f;
  unsigned r = v.u + 0x7FFF + ((v.u >> 16) & 1);
  return (unsigned short)(r >> 16);
}
__device__ __forceinline__ float b2f(unsigned short u) {
  union { unsigned u; float f; } v; v.u = (unsigned)u << 16;
  return v.f;
}

// ---------------------------------------------- weight convert + transpose
// all 6 weights in one launch: fp32 [K][N] -> bf16 [N][K]
// ranges: Wv [0,65536) Woff [65536,131072) Wattn [131072,163840)
//         Wo [163840,229376) W1 [229376,491520) W2 [491520,753664)
__global__ void wconv_all(const float* __restrict__ Wv, const float* __restrict__ Woff,
                          const float* __restrict__ Wattn, const float* __restrict__ Wo,
                          const float* __restrict__ W1, const float* __restrict__ W2,
                          unsigned short* __restrict__ dstbase) {
  int idx = blockIdx.x * 256 + threadIdx.x;  // 0 .. 753664
  const float* src; int K, N, off;
  if (idx < 65536)       { src = Wv;    K = 256;  N = 256;  off = 0;      }
  else if (idx < 131072) { src = Woff;  K = 256;  N = 256;  off = 65536;  idx -= 65536; }
  else if (idx < 163840) { src = Wattn; K = 256;  N = 128;  off = 131072; idx -= 131072; }
  else if (idx < 229376) { src = Wo;    K = 256;  N = 256;  off = 163840; idx -= 163840; }
  else if (idx < 491520) { src = W1;    K = 256;  N = 1024; off = 229376; idx -= 229376; }
  else if (idx < 753664) { src = W2;    K = 1024; N = 256;  off = 491520; idx -= 491520; }
  else return;
  int k = idx / N, n = idx - k * N;
  dstbase[off + (size_t)n * K + k] = f2b(src[idx]);
}

// ---------------------------------------------------------------- LayerNorm
// one token per 64-lane wave; lane handles 4 consecutive floats.
// LN1: writes v (bf16) and q = v + pos (bf16)
__global__ void ln1_kernel(const float* __restrict__ x, const float* __restrict__ pos,
                           const float* __restrict__ w, const float* __restrict__ b,
                           unsigned short* __restrict__ vb, unsigned short* __restrict__ qb) {
  int t = threadIdx.x;
  int tkn = blockIdx.x * 4 + (t >> 6);
  int lane = t & 63;
  size_t base = (size_t)tkn * DMODEL + lane * 4;
  float4 xv = *(const float4*)&x[base];
  float s1 = xv.x + xv.y + xv.z + xv.w;
  float s2 = xv.x * xv.x + xv.y * xv.y + xv.z * xv.z + xv.w * xv.w;
  #pragma unroll
  for (int off = 32; off; off >>= 1) {
    s1 += __shfl_down(s1, off);
    s2 += __shfl_down(s2, off);
  }
  s1 = __shfl(s1, 0); s2 = __shfl(s2, 0);
  float m   = s1 * (1.0f / DMODEL);
  float var = s2 * (1.0f / DMODEL) - m * m;
  float rs  = rsqrtf(var + 1e-5f);
  float4 wv = *(const float4*)&w[lane * 4];
  float4 bv = *(const float4*)&b[lane * 4];
  float4 pv = *(const float4*)&pos[base];
  float o0 = (xv.x - m) * rs * wv.x + bv.x;
  float o1 = (xv.y - m) * rs * wv.y + bv.y;
  float o2 = (xv.z - m) * rs * wv.z + bv.z;
  float o3 = (xv.w - m) * rs * wv.w + bv.w;
  ushort4 vo = {f2b(o0), f2b(o1), f2b(o2), f2b(o3)};
  ushort4 qo = {f2b(o0 + pv.x), f2b(o1 + pv.y), f2b(o2 + pv.z), f2b(o3 + pv.w)};
  *(ushort4*)&vb[base] = vo;
  *(ushort4*)&qb[base] = qo;
}

__global__ void ln2_kernel(const float* __restrict__ x, const float* __restrict__ w,
                           const float* __restrict__ b, unsigned short* __restrict__ yb) {
  int t = threadIdx.x;
  int tkn = blockIdx.x * 4 + (t >> 6);
  int lane = t & 63;
  size_t base = (size_t)tkn * DMODEL + lane * 4;
  float4 xv = *(const float4*)&x[base];
  float s1 = xv.x + xv.y + xv.z + xv.w;
  float s2 = xv.x * xv.x + xv.y * xv.y + xv.z * xv.z + xv.w * xv.w;
  #pragma unroll
  for (int off = 32; off; off >>= 1) {
    s1 += __shfl_down(s1, off);
    s2 += __shfl_down(s2, off);
  }
  s1 = __shfl(s1, 0); s2 = __shfl(s2, 0);
  float m   = s1 * (1.0f / DMODEL);
  float var = s2 * (1.0f / DMODEL) - m * m;
  float rs  = rsqrtf(var + 1e-5f);
  float4 wv = *(const float4*)&w[lane * 4];
  float4 bv = *(const float4*)&b[lane * 4];
  ushort4 vo = {f2b((xv.x - m) * rs * wv.x + bv.x), f2b((xv.y - m) * rs * wv.y + bv.y),
                f2b((xv.z - m) * rs * wv.z + bv.z), f2b((xv.w - m) * rs * wv.w + bv.w)};
  *(ushort4*)&yb[base] = vo;
}

// ------------------------------------------------------- bf16 MFMA GEMM
// C[M x N] = act(A[M x K] @ Bt[N x K]^T + bias) (+ addsrc)
__global__ void gemm_bf16(const unsigned short* __restrict__ A,
                          const unsigned short* __restrict__ Bt,
                          const float* __restrict__ bias, const float* __restrict__ addsrc,
                          float* __restrict__ Cf, unsigned short* __restrict__ Cb,
                          int K, int N, int relu) {
  __shared__ unsigned short As[128 * 72];
  __shared__ unsigned short Bs[128 * 72];
  int t    = threadIdx.x;
  int row0 = blockIdx.x * 128;
  int col0 = blockIdx.y * 128;
  int w    = t >> 6;
  int l    = t & 63;
  int wm   = w >> 1, wn = w & 1;
  int lr   = l & 15;
  int kq   = l >> 4;

  f32x4 acc[4][4];
  #pragma unroll
  for (int i = 0; i < 4; ++i)
    #pragma unroll
    for (int j = 0; j < 4; ++j) acc[i][j] = (f32x4){0.f, 0.f, 0.f, 0.f};

  for (int k0 = 0; k0 < K; k0 += 64) {
    #pragma unroll
    for (int i = 0; i < 4; ++i) {
      int c = i * 256 + t;
      int row = c >> 3, seg = c & 7;
      float4 va = *(const float4*)&A [(size_t)(row0 + row) * K + k0 + seg * 8];
      float4 vb = *(const float4*)&Bt[(size_t)(col0 + row) * K + k0 + seg * 8];
      *(float4*)&As[row * 72 + seg * 8] = va;
      *(float4*)&Bs[row * 72 + seg * 8] = vb;
    }
    __syncthreads();
    #pragma unroll
    for (int kk = 0; kk < 2; ++kk) {
      b16x8 aF[4], bF[4];
      #pragma unroll
      for (int i = 0; i < 4; ++i)
        aF[i] = *(const b16x8*)&As[(wm * 64 + i * 16 + lr) * 72 + kk * 32 + kq * 8];
      #pragma unroll
      for (int j = 0; j < 4; ++j)
        bF[j] = *(const b16x8*)&Bs[(wn * 64 + j * 16 + lr) * 72 + kk * 32 + kq * 8];
      #pragma unroll
      for (int i = 0; i < 4; ++i)
        #pragma unroll
        for (int j = 0; j < 4; ++j)
          acc[i][j] = __builtin_amdgcn_mfma_f32_16x16x32_bf16(aF[i], bF[j], acc[i][j], 0, 0, 0);
    }
    __syncthreads();
  }

  #pragma unroll
  for (int j = 0; j < 4; ++j) {
    int colg = col0 + wn * 64 + j * 16 + lr;
    float bcol = bias[colg];
    #pragma unroll
    for (int i = 0; i < 4; ++i) {
      int r0g = row0 + wm * 64 + i * 16 + kq * 4;
      #pragma unroll
      for (int r = 0; r < 4; ++r) {
        int rowg = r0g + r;
        float o = acc[i][j][r] + bcol;
        if (relu) o = fmaxf(o, 0.0f);
        if (addsrc) o += addsrc[(size_t)rowg * N + colg];
        if (Cf) Cf[(size_t)rowg * N + colg] = o;
        if (Cb) Cb[(size_t)rowg * N + colg] = f2b(o);
      }
    }
  }
}

// --------------------------------------------------- MSDA sampling + softmax
// block = token. Phase 1 (128 thr): (weight, byte-offset) pairs -> LDS.
// Phase 2 (256 thr): lane = (h, dpair, tap-half); u32 gathers of 2 bf16.
__global__ void msda_kernel(const unsigned short* __restrict__ value,
                            const unsigned short* __restrict__ offb,
                            const unsigned short* __restrict__ awb,
                            const float* __restrict__ ref,
                            unsigned short* __restrict__ outb) {
  __shared__ int2 P[512];   // {w bits, byte offset}
  int tkn = blockIdx.x;
  int t   = threadIdx.x;
  int b   = (tkn >= N_TOTAL) ? 1 : 0;

  if (t < 128) {
    int h = t >> 4, s = t & 15, lev = s >> 2, p = s & 3;
    float lg = b2f(awb[(size_t)tkn * 128 + h * 16 + s]);
    float mx = lg;
    #pragma unroll
    for (int m = 1; m < 16; m <<= 1) mx = fmaxf(mx, __shfl_xor(mx, m, 16));
    float e = __expf(lg - mx);
    float sum = e;
    #pragma unroll
    for (int m = 1; m < 16; m <<= 1) sum += __shfl_xor(sum, m, 16);
    float aw = e / sum;

    const int HL[4] = {128, 64, 32, 16};
    const int ST[4] = {0, 16384, 20480, 21504};
    int Wl = HL[lev];
    float rx = ref[(size_t)tkn * 8 + lev * 2 + 0];
    float ry = ref[(size_t)tkn * 8 + lev * 2 + 1];
    float ox = b2f(offb[(size_t)tkn * 256 + h * 32 + lev * 8 + p * 2 + 0]);
    float oy = b2f(offb[(size_t)tkn * 256 + h * 32 + lev * 8 + p * 2 + 1]);
    float x = rx * (float)Wl + ox - 0.5f;   // Hl == Wl all levels
    float y = ry * (float)Wl + oy - 0.5f;
    float x0f = floorf(x), y0f = floorf(y);
    float wx = x - x0f, wy = y - y0f;
    int x0 = (int)x0f, y0 = (int)y0f;
    float wt[4] = {(1.f - wx) * (1.f - wy), wx * (1.f - wy),
                   (1.f - wx) * wy, wx * wy};
    int base = b * N_TOTAL + ST[lev];
    #pragma unroll
    for (int tp = 0; tp < 4; ++tp) {
      int xi = x0 + (tp & 1), yi = y0 + (tp >> 1);
      bool ok = (xi >= 0) & (xi < Wl) & (yi >= 0) & (yi < Wl);
      float wgt = ok ? aw * wt[tp] : 0.f;
      int boff  = ok ? (((base + yi * Wl + xi) * 256 + h * 32) * 2) : 0;
      P[t * 4 + tp] = (int2){__float_as_int(wgt), boff};
    }
  }
  __syncthreads();

  int h = t >> 5, g = t & 31, dp = g & 15, half = g >> 4;
  int o = h * 64 + half * 32;
  int doff = dp * 4;  // byte offset of d-pair within the 64B head segment
  const char* vbase = (const char*)value;
  float accL = 0.f, accH = 0.f;
  #pragma unroll 8
  for (int j = 0; j < 32; ++j) {
    int2 pr = P[o + j];
    float wgt = __int_as_float(pr.x);
    unsigned v = *(const unsigned*)(vbase + (size_t)(unsigned)pr.y + doff);
    union { unsigned u; float f; } lo, hi;
    lo.u = v << 16;
    hi.u = v & 0xffff0000u;
    accL += wgt * lo.f;
    accH += wgt * hi.f;
  }
  accL += __shfl_xor(accL, 16);
  accH += __shfl_xor(accH, 16);
  if (half == 0) {
    unsigned pk = (unsigned)f2b(accL) | ((unsigned)f2b(accH) << 16);
    *(unsigned*)&outb[(size_t)tkn * 256 + h * 32 + dp * 2] = pk;
  }
}

// --------------------------------------------------------------- launcher
extern "C" void kernel_launch(void* const* d_in, const int* in_sizes, int n_in,
                              void* d_out, int out_size, void* d_ws, size_t ws_size,
                              hipStream_t stream) {
  const float* embed = (const float*)d_in[0];
  const float* pos   = (const float*)d_in[1];
  const float* refp  = (const float*)d_in[2];
  const float* ln1w  = (const float*)d_in[3];
  const float* ln1b  = (const float*)d_in[4];
  const float* ln2w  = (const float*)d_in[5];
  const float* ln2b  = (const float*)d_in[6];
  const float* Wv    = (const float*)d_in[7];
  const float* bv    = (const float*)d_in[8];
  const float* Woff  = (const float*)d_in[9];
  const float* boff  = (const float*)d_in[10];
  const float* Wattn = (const float*)d_in[11];
  const float* battn = (const float*)d_in[12];
  const float* Wo    = (const float*)d_in[13];
  const float* bo    = (const float*)d_in[14];
  const float* W1    = (const float*)d_in[15];
  const float* b1    = (const float*)d_in[16];
  const float* W2    = (const float*)d_in[17];
  const float* b2    = (const float*)d_in[18];
  float* out = (float*)d_out;
  float* ws  = (float*)d_ws;

  const size_t U = (size_t)M_TOT * DMODEL;  // 11,141,120 floats
  // [0, 2U) gather-phase bf16 buffers, later overlaid by hid16
  unsigned short* valb16 = (unsigned short*)ws;               // 0.5U floats
  unsigned short* offb16 = (unsigned short*)(ws + U / 2);     // 0.5U
  unsigned short* awb16  = (unsigned short*)(ws + U);         // 0.25U
  unsigned short* msdab  = (unsigned short*)(ws + U + U / 4); // 0.5U
  unsigned short* hid16  = (unsigned short*)ws;               // [0, 2U) after msda
  float*          embed2 = ws + 2 * U;                        // [2U, 3U) fp32
  unsigned short* vb16   = (unsigned short*)(ws + 3 * U);         // 0.5U
  unsigned short* qb16   = (unsigned short*)(ws + 3 * U + U / 2); // 0.5U
  unsigned short* fb16   = (unsigned short*)(ws + 4 * U);         // 0.5U
  unsigned short* wbuf   = (unsigned short*)(ws + 4 * U + U / 2);

  unsigned short* Wvt    = wbuf;            // offsets match wconv_all
  unsigned short* Wofft  = wbuf + 65536;
  unsigned short* Wattnt = wbuf + 131072;
  unsigned short* Wot    = wbuf + 163840;
  unsigned short* W1t    = wbuf + 229376;
  unsigned short* W2t    = wbuf + 491520;

  wconv_all<<<(753664 + 255) / 256, 256, 0, stream>>>(Wv, Woff, Wattn, Wo, W1, W2, wbuf);

  ln1_kernel<<<M_TOT / 4, 256, 0, stream>>>(embed, pos, ln1w, ln1b, vb16, qb16);

  gemm_bf16<<<dim3(M_TOT / 128, 2), 256, 0, stream>>>(
      vb16, Wvt, bv, nullptr, nullptr, valb16, 256, 256, 0);
  gemm_bf16<<<dim3(M_TOT / 128, 2), 256, 0, stream>>>(
      qb16, Wofft, boff, nullptr, nullptr, offb16, 256, 256, 0);
  gemm_bf16<<<dim3(M_TOT / 128, 1), 256, 0, stream>>>(
      qb16, Wattnt, battn, nullptr, nullptr, awb16, 256, 128, 0);

  msda_kernel<<<M_TOT, 256, 0, stream>>>(valb16, offb16, awb16, refp, msdab);

  gemm_bf16<<<dim3(M_TOT / 128, 2), 256, 0, stream>>>(
      msdab, Wot, bo, embed, embed2, nullptr, 256, 256, 0);

  ln2_kernel<<<M_TOT / 4, 256, 0, stream>>>(embed2, ln2w, ln2b, fb16);

  gemm_bf16<<<dim3(M_TOT / 128, 8), 256, 0, stream>>>(
      fb16, W1t, b1, nullptr, nullptr, hid16, 256, 1024, 1);
  gemm_bf16<<<dim3(M_TOT / 128, 2), 256, 0, stream>>>(
      hid16, W2t, b2, embed2, out, nullptr, 1024, 256, 0);
}